// Round 19
// baseline (50.331 us; speedup 1.0000x reference)
//
#include <hip/hip_runtime.h>

// Fully fused per-batch kernel: QKV projection + causal attention.
// R16 base, with W-fragments loaded per-chunk DIRECTLY from global (L2-hot,
// contiguous 1KB/wave) instead of staged through LDS — barriers gate only x.
// fp16 MFMA 16x16x32: A row=lane&15,k=8*(lane>>4)+i; B col=lane&15,k=8*(lane>>4)+i;
//                     C/D col=lane&15, row=4*(lane>>4)+reg.

#define B_ 256
#define T_ 256
#define C_ 384
#define H_ 64

typedef __attribute__((ext_vector_type(4))) float     f32x4;
typedef __attribute__((ext_vector_type(8))) _Float16  f16x8;

#define MFMA16(a, b, c) __builtin_amdgcn_mfma_f32_16x16x32_f16((a), (b), (c), 0, 0, 0)
#define LGKM_BARRIER() do { asm volatile("s_waitcnt lgkmcnt(0)" ::: "memory"); \
                            __builtin_amdgcn_s_barrier(); } while (0)

// ---------------- LDS layout (halfs) ----------------
constexpr int SQ = 72;                      // Qs/Ks stride
constexpr int SV = 264;                     // Vt stride
constexpr int SP = 72;                      // Ps stride
constexpr int OFF_K = 256 * SQ;             // 18432
constexpr int OFF_V = 2 * 256 * SQ;         // 36864
constexpr int OFF_X = OFF_V + 64 * SV;      // 53760 (x chunk [256][40]; Ps reuses)
constexpr int SMEM_HALFS = OFF_X + 8 * 32 * SP;   // 72192 (covers Ps span)
constexpr int SMEM_BYTES = SMEM_HALFS * 2;        // 144384 B

// ================= k0: W -> Wf (16x16 fragment layout; verified) =============
// Wf[e]: e = ((nt*12+kk)*64 + lane)*8 + i ; lane (l15,hi) holds elem
// col=nt*16+l15, k=kk*32+hi*8+i. One (nt,kk) chunk = contiguous 1KB wave-load.
__global__ void w_fragpack(const float* __restrict__ Wq,
                           const float* __restrict__ Wk,
                           const float* __restrict__ Wv,
                           _Float16* __restrict__ Wf) {
    int e = blockIdx.x * 256 + threadIdx.x;      // 0..73727
    int i    = e & 7;
    int lane = (e >> 3) & 63;
    int l15  = lane & 15, hi = lane >> 4;
    int cid  = e >> 9;                            // nt*12 + kk
    int kk   = cid % 12;
    int nt   = cid / 12;
    int col  = nt * 16 + l15;
    int p    = col >> 6;
    int h    = col & 63;
    int k    = kk * 32 + hi * 8 + i;
    const float* W = (p == 0) ? Wq : (p == 1) ? Wk : Wv;
    Wf[e] = (_Float16)W[k * 64 + h];
}

// ---- x staging helpers (32-col chunks, R16-verified addressing) ----
__device__ __forceinline__ void issue_chunk(const float* xb, int tid, int c,
                                            float4 (&xu)[4])
{
    #pragma unroll
    for (int i = 0; i < 2; ++i) {
        int id = tid + i * 512, row = id >> 2, g = id & 3;
        const float* gp = xb + row * C_ + c * 32 + g * 8;
        xu[2 * i]     = *(const float4*)gp;
        xu[2 * i + 1] = *(const float4*)(gp + 4);
    }
}

__device__ __forceinline__ void write_chunk(_Float16* XB, int tid,
                                            const float4 (&xu)[4])
{
    #pragma unroll
    for (int i = 0; i < 2; ++i) {
        int id = tid + i * 512, row = id >> 2, g = id & 3;
        const float4& a = xu[2 * i];
        const float4& b = xu[2 * i + 1];
        f16x8 hv = {(_Float16)a.x, (_Float16)a.y, (_Float16)a.z, (_Float16)a.w,
                    (_Float16)b.x, (_Float16)b.y, (_Float16)b.z, (_Float16)b.w};
        *(f16x8*)(XB + row * 40 + g * 8) = hv;
    }
}

// ================= fused kernel: one block per batch =================
__global__ __launch_bounds__(512, 1) void head_fused(
    const float* __restrict__ x, const _Float16* __restrict__ Wf,
    float* __restrict__ out)
{
    extern __shared__ _Float16 sm[];
    _Float16* Qs = sm;                 // [256][SQ], pre-scaled
    _Float16* Ks = sm + OFF_K;         // [256][SQ]
    _Float16* Vt = sm + OFF_V;         // [64][SV]
    _Float16* XB = sm + OFF_X;         // [256][40] per-chunk x tile
    _Float16* Ps = sm + OFF_X;         // phase-B P bounce (reuses XB span)

    const int tid = threadIdx.x, lane = tid & 63, wid = tid >> 6;
    const int lo = lane & 15, hi = lane >> 4;
    const int b = blockIdx.x;
    const float* xb = x + (size_t)b * T_ * C_;
    const _Float16* wb = Wf + (size_t)lane * 8;

    // ---- prologue: issue x chunks 0,1 (2-deep), write chunk 0 ----
    float4 xA[4], xB2[4];
    issue_chunk(xb, tid, 0, xA);
    issue_chunk(xb, tid, 1, xB2);
    write_chunk(XB, tid, xA);                     // counted-vmcnt wait (set A)
    LGKM_BARRIER();

    // ---- K-chunk loop: barriers gate x only; W streams from L2 ----
    f32x4 acc[12][2] = {};                 // [col-tile][row-slab]
    #pragma unroll
    for (int c = 0; c < 12; ++c) {
        // issue x chunk c+2 into the parity set freed by chunk c's write
        if (c + 2 < 12) {
            if ((c & 1) == 0) issue_chunk(xb, tid, c + 2, xA);
            else              issue_chunk(xb, tid, c + 2, xB2);
        }

        // W fragments for chunk c: 12 independent contiguous 1KB wave-loads
        f16x8 wf[12];
        #pragma unroll
        for (int nt = 0; nt < 12; ++nt)
            wf[nt] = *(const f16x8*)(wb + (size_t)(nt * 12 + c) * 512);

        // compute chunk c
        f16x8 a0 = *(const f16x8*)(XB + (32 * wid + lo) * 40 + hi * 8);
        f16x8 a1 = *(const f16x8*)(XB + (32 * wid + 16 + lo) * 40 + hi * 8);
        #pragma unroll
        for (int nt = 0; nt < 8; ++nt) {           // Q (0-3), K (4-7): D[t][n]
            acc[nt][0] = MFMA16(a0, wf[nt], acc[nt][0]);
            acc[nt][1] = MFMA16(a1, wf[nt], acc[nt][1]);
        }
        #pragma unroll
        for (int nt = 8; nt < 12; ++nt) {          // V: D[h][t] (operand swap)
            acc[nt][0] = MFMA16(wf[nt], a0, acc[nt][0]);
            acc[nt][1] = MFMA16(wf[nt], a1, acc[nt][1]);
        }

        if (c < 11) {
            LGKM_BARRIER();                        // all waves done reading XB
            if ((c & 1) == 0) write_chunk(XB, tid, xB2);
            else              write_chunk(XB, tid, xA);
            LGKM_BARRIER();                        // writes visible
        }
    }

    // ---- epilogue: acc -> Qs (pre-scaled) / Ks / Vt ----
    #pragma unroll
    for (int nt = 0; nt < 4; ++nt)
        #pragma unroll
        for (int s = 0; s < 2; ++s)
            #pragma unroll
            for (int reg = 0; reg < 4; ++reg) {
                int t = 32 * wid + s * 16 + 4 * hi + reg;
                Qs[t * SQ + nt * 16 + lo] = (_Float16)(0.125f * acc[nt][s][reg]);
            }
    #pragma unroll
    for (int nt = 4; nt < 8; ++nt)
        #pragma unroll
        for (int s = 0; s < 2; ++s)
            #pragma unroll
            for (int reg = 0; reg < 4; ++reg) {
                int t = 32 * wid + s * 16 + 4 * hi + reg;
                Ks[t * SQ + (nt - 4) * 16 + lo] = (_Float16)acc[nt][s][reg];
            }
    #pragma unroll
    for (int nt = 8; nt < 12; ++nt)
        #pragma unroll
        for (int s = 0; s < 2; ++s)
            #pragma unroll
            for (int reg = 0; reg < 4; ++reg) {
                int h = (nt - 8) * 16 + 4 * hi + reg;
                int t = 32 * wid + s * 16 + lo;
                Vt[h * SV + t] = (_Float16)acc[nt][s][reg];
            }
    __syncthreads();

    // ---- phase B: causal attention (verified structure, LDS operands) ----
    const int ctmax = 2 * wid + 1;

    f16x8 aq[2][2];
    #pragma unroll
    for (int rt = 0; rt < 2; ++rt)
        #pragma unroll
        for (int ks = 0; ks < 2; ++ks)
            aq[rt][ks] = *(const f16x8*)(Qs + (32 * wid + 16 * rt + lo) * SQ + 32 * ks + 8 * hi);

    f32x4 sacc[2][16] = {};
    #pragma unroll
    for (int ct = 0; ct < 16; ++ct) {
        if (ct <= ctmax) {
            #pragma unroll
            for (int ks = 0; ks < 2; ++ks) {
                f16x8 bk = *(const f16x8*)(Ks + (16 * ct + lo) * SQ + 32 * ks + 8 * hi);
                sacc[0][ct] = MFMA16(aq[0][ks], bk, sacc[0][ct]);
                sacc[1][ct] = MFMA16(aq[1][ks], bk, sacc[1][ct]);
            }
        }
    }

    #pragma unroll
    for (int rt = 0; rt < 2; ++rt) {
        #pragma unroll
        for (int reg = 0; reg < 4; ++reg) {
            const int rowg = 32 * wid + 16 * rt + 4 * hi + reg;
            float m = -1e30f;
            #pragma unroll
            for (int ct = 0; ct < 16; ++ct) if (ct <= ctmax) {
                float v = sacc[rt][ct][reg];
                v = (16 * ct + lo <= rowg) ? v : -1e30f;
                sacc[rt][ct][reg] = v;
                m = fmaxf(m, v);
            }
            #pragma unroll
            for (int s = 1; s < 16; s <<= 1) m = fmaxf(m, __shfl_xor(m, s, 16));
            float l = 0.f;
            #pragma unroll
            for (int ct = 0; ct < 16; ++ct) if (ct <= ctmax) {
                float v = sacc[rt][ct][reg];
                float p = (v > -1e29f) ? __expf(v - m) : 0.f;
                sacc[rt][ct][reg] = p;
                l += p;
            }
            #pragma unroll
            for (int s = 1; s < 16; s <<= 1) l += __shfl_xor(l, s, 16);
            float rinv = 1.f / l;
            #pragma unroll
            for (int ct = 0; ct < 16; ++ct) if (ct <= ctmax) sacc[rt][ct][reg] *= rinv;
        }
    }

    f32x4 oacc[2][4] = {};
    _Float16* Pw = Ps + wid * 32 * SP;
    const int kcmax = ctmax >> 2;
    #pragma unroll
    for (int kc = 0; kc < 4; ++kc) {
        if (kc <= kcmax) {
            #pragma unroll
            for (int rt = 0; rt < 2; ++rt)
                #pragma unroll
                for (int cc = 0; cc < 4; ++cc) {
                    const int ct = 4 * kc + cc;
                    #pragma unroll
                    for (int reg = 0; reg < 4; ++reg) {
                        float v = (ct <= ctmax) ? sacc[rt][ct][reg] : 0.f;
                        Pw[(16 * rt + 4 * hi + reg) * SP + cc * 16 + lo] = (_Float16)v;
                    }
                }
            asm volatile("s_waitcnt lgkmcnt(0)" ::: "memory");
            #pragma unroll
            for (int ks = 0; ks < 2; ++ks) {
                f16x8 p0 = *(const f16x8*)(Pw + lo * SP + 32 * ks + 8 * hi);
                f16x8 p1 = *(const f16x8*)(Pw + (16 + lo) * SP + 32 * ks + 8 * hi);
                #pragma unroll
                for (int ht = 0; ht < 4; ++ht) {
                    f16x8 bv = *(const f16x8*)(Vt + (16 * ht + lo) * SV + 64 * kc + 32 * ks + 8 * hi);
                    oacc[0][ht] = MFMA16(p0, bv, oacc[0][ht]);
                    oacc[1][ht] = MFMA16(p1, bv, oacc[1][ht]);
                }
            }
            asm volatile("s_waitcnt lgkmcnt(0)" ::: "memory");
        }
    }

    float* ob = out + (size_t)b * (T_ * H_);
    #pragma unroll
    for (int rt = 0; rt < 2; ++rt)
        #pragma unroll
        for (int ht = 0; ht < 4; ++ht)
            #pragma unroll
            for (int reg = 0; reg < 4; ++reg) {
                const int t = 32 * wid + 16 * rt + 4 * hi + reg;
                ob[t * H_ + 16 * ht + lo] = oacc[rt][ht][reg];
            }
}

extern "C" void kernel_launch(void* const* d_in, const int* in_sizes, int n_in,
                              void* d_out, int out_size, void* d_ws, size_t ws_size,
                              hipStream_t stream) {
    const float* x  = (const float*)d_in[0];
    const float* Wq = (const float*)d_in[1];
    const float* Wk = (const float*)d_in[2];
    const float* Wv = (const float*)d_in[3];
    float* out = (float*)d_out;
    (void)in_sizes; (void)n_in; (void)out_size; (void)ws_size;

    _Float16* Wf = (_Float16*)d_ws;                 // 147456 B

    w_fragpack<<<dim3(288), dim3(256), 0, stream>>>(Wq, Wk, Wv, Wf);
    hipFuncSetAttribute(reinterpret_cast<const void*>(head_fused),
                        hipFuncAttributeMaxDynamicSharedMemorySize, SMEM_BYTES);
    head_fused<<<dim3(B_), dim3(512), SMEM_BYTES, stream>>>(x, Wf, out);
}

// Round 20
// 41.455 us; speedup vs baseline: 1.2141x; 1.2141x over previous
//
#include <hip/hip_runtime.h>

// Fully fused per-batch kernel: QKV projection + causal attention, intermediates
// in LDS. (= R16, the session's best measured state: 41.1 us.)
// k0 packs W into 16x16 MFMA fragment order. Phase A: 12 K-chunks, 2-deep
// register prefetch (parity sets), raw s_barrier + lgkmcnt-only drain so global
// prefetch loads stay in flight across barriers. Phase B: causal attention with
// column-tile skipping, wave-parallel softmax, P-bounce through per-wave LDS.
// fp16 MFMA 16x16x32: A row=lane&15,k=8*(lane>>4)+i; B col=lane&15,k=8*(lane>>4)+i;
//                     C/D col=lane&15, row=4*(lane>>4)+reg.

#define B_ 256
#define T_ 256
#define C_ 384
#define H_ 64

typedef __attribute__((ext_vector_type(4))) float     f32x4;
typedef __attribute__((ext_vector_type(8))) _Float16  f16x8;

#define MFMA16(a, b, c) __builtin_amdgcn_mfma_f32_16x16x32_f16((a), (b), (c), 0, 0, 0)
#define LGKM_BARRIER() do { asm volatile("s_waitcnt lgkmcnt(0)" ::: "memory"); \
                            __builtin_amdgcn_s_barrier(); } while (0)

// ---------------- LDS layout (halfs) ----------------
constexpr int SQ = 72;                      // Qs/Ks stride
constexpr int SV = 264;                     // Vt stride
constexpr int SP = 72;                      // Ps stride
constexpr int OFF_K = 256 * SQ;             // 18432
constexpr int OFF_V = 2 * 256 * SQ;         // 36864
constexpr int OFF_X = OFF_V + 64 * SV;      // 53760 (x chunk [256][40]; Ps reuses)
constexpr int OFF_W = OFF_X + 256 * 40;     // 64000 (W chunk, 12 nt x 64 lanes x 8)
constexpr int SMEM_HALFS = OFF_X + 8 * 32 * SP;   // 72192 (covers Ps span)
constexpr int SMEM_BYTES = SMEM_HALFS * 2;        // 144384 B

// ================= k0: W -> Wf (16x16 fragment layout; verified) =============
__global__ void w_fragpack(const float* __restrict__ Wq,
                           const float* __restrict__ Wk,
                           const float* __restrict__ Wv,
                           _Float16* __restrict__ Wf) {
    int e = blockIdx.x * 256 + threadIdx.x;      // 0..73727
    int i    = e & 7;
    int lane = (e >> 3) & 63;
    int l15  = lane & 15, hi = lane >> 4;
    int cid  = e >> 9;                            // nt*12 + kk
    int kk   = cid % 12;
    int nt   = cid / 12;
    int col  = nt * 16 + l15;
    int p    = col >> 6;
    int h    = col & 63;
    int k    = kk * 32 + hi * 8 + i;
    const float* W = (p == 0) ? Wq : (p == 1) ? Wk : Wv;
    Wf[e] = (_Float16)W[k * 64 + h];
}

// ---- staging helpers (constant-indexed arrays -> registers) ----
__device__ __forceinline__ void issue_chunk(const float* xb, const _Float16* Wf,
    int tid, int c, float4 (&xu)[4], f16x8& w0, f16x8& w1)
{
    #pragma unroll
    for (int i = 0; i < 2; ++i) {
        int id = tid + i * 512, row = id >> 2, g = id & 3;
        const float* gp = xb + row * C_ + c * 32 + g * 8;
        xu[2 * i]     = *(const float4*)gp;
        xu[2 * i + 1] = *(const float4*)(gp + 4);
    }
    { int nt = tid >> 6, l = tid & 63;
      w0 = *(const f16x8*)(Wf + ((size_t)(nt * 12 + c) * 64 + l) * 8); }
    if (tid < 256) { int id = 512 + tid, nt = id >> 6, l = id & 63;
      w1 = *(const f16x8*)(Wf + ((size_t)(nt * 12 + c) * 64 + l) * 8); }
}

__device__ __forceinline__ void write_chunk(_Float16* XB, _Float16* WS,
    int tid, const float4 (&xu)[4], const f16x8& w0, const f16x8& w1)
{
    #pragma unroll
    for (int i = 0; i < 2; ++i) {
        int id = tid + i * 512, row = id >> 2, g = id & 3;
        const float4& a = xu[2 * i];
        const float4& b = xu[2 * i + 1];
        f16x8 hv = {(_Float16)a.x, (_Float16)a.y, (_Float16)a.z, (_Float16)a.w,
                    (_Float16)b.x, (_Float16)b.y, (_Float16)b.z, (_Float16)b.w};
        *(f16x8*)(XB + row * 40 + g * 8) = hv;
    }
    *(f16x8*)(WS + tid * 8) = w0;
    if (tid < 256) *(f16x8*)(WS + (512 + tid) * 8) = w1;
}

// ================= fused kernel: one block per batch =================
__global__ __launch_bounds__(512, 1) void head_fused(
    const float* __restrict__ x, const _Float16* __restrict__ Wf,
    float* __restrict__ out)
{
    extern __shared__ _Float16 sm[];
    _Float16* Qs = sm;                 // [256][SQ], pre-scaled
    _Float16* Ks = sm + OFF_K;         // [256][SQ]
    _Float16* Vt = sm + OFF_V;         // [64][SV]
    _Float16* XB = sm + OFF_X;         // [256][40] per-chunk x tile
    _Float16* WS = sm + OFF_W;         // [12][64][8] per-chunk W frags
    _Float16* Ps = sm + OFF_X;         // phase-B P bounce (reuses XB/WS span)

    const int tid = threadIdx.x, lane = tid & 63, wid = tid >> 6;
    const int lo = lane & 15, hi = lane >> 4;
    const int b = blockIdx.x;
    const float* xb = x + (size_t)b * T_ * C_;

    // ---- prologue: issue chunks 0,1 (2-deep), write chunk 0 ----
    float4 xA[4], xB2[4];
    f16x8  wA0, wA1, wB0, wB1;
    issue_chunk(xb, Wf, tid, 0, xA, wA0, wA1);
    issue_chunk(xb, Wf, tid, 1, xB2, wB0, wB1);
    write_chunk(XB, WS, tid, xA, wA0, wA1);       // auto counted-vmcnt wait (set A)
    LGKM_BARRIER();

    // ---- K-chunk loop: 2 raw barriers/chunk, loads stay in flight ----
    f32x4 acc[12][2] = {};                 // [col-tile][row-slab]
    #pragma unroll
    for (int c = 0; c < 12; ++c) {
        // issue chunk c+2 into the parity set freed by chunk c's write
        if (c + 2 < 12) {
            if ((c & 1) == 0) issue_chunk(xb, Wf, tid, c + 2, xA, wA0, wA1);
            else              issue_chunk(xb, Wf, tid, c + 2, xB2, wB0, wB1);
        }

        // compute chunk c
        f16x8 a0 = *(const f16x8*)(XB + (32 * wid + lo) * 40 + hi * 8);
        f16x8 a1 = *(const f16x8*)(XB + (32 * wid + 16 + lo) * 40 + hi * 8);
        #pragma unroll
        for (int nt = 0; nt < 8; ++nt) {           // Q (0-3), K (4-7): D[t][n]
            f16x8 wf = *(const f16x8*)(WS + (nt * 64 + lane) * 8);
            acc[nt][0] = MFMA16(a0, wf, acc[nt][0]);
            acc[nt][1] = MFMA16(a1, wf, acc[nt][1]);
        }
        #pragma unroll
        for (int nt = 8; nt < 12; ++nt) {          // V: D[h][t] (operand swap)
            f16x8 wf = *(const f16x8*)(WS + (nt * 64 + lane) * 8);
            acc[nt][0] = MFMA16(wf, a0, acc[nt][0]);
            acc[nt][1] = MFMA16(wf, a1, acc[nt][1]);
        }

        if (c < 11) {
            LGKM_BARRIER();                        // all waves done reading XB/WS
            // write chunk c+1 from set ((c+1)&1); data issued ~2 chunks ago
            if ((c & 1) == 0) write_chunk(XB, WS, tid, xB2, wB0, wB1);
            else              write_chunk(XB, WS, tid, xA, wA0, wA1);
            LGKM_BARRIER();                        // writes visible to all waves
        }
    }

    // ---- epilogue: acc -> Qs (pre-scaled) / Ks / Vt (disjoint from XB/WS) ----
    #pragma unroll
    for (int nt = 0; nt < 4; ++nt)
        #pragma unroll
        for (int s = 0; s < 2; ++s)
            #pragma unroll
            for (int reg = 0; reg < 4; ++reg) {
                int t = 32 * wid + s * 16 + 4 * hi + reg;
                Qs[t * SQ + nt * 16 + lo] = (_Float16)(0.125f * acc[nt][s][reg]);
            }
    #pragma unroll
    for (int nt = 4; nt < 8; ++nt)
        #pragma unroll
        for (int s = 0; s < 2; ++s)
            #pragma unroll
            for (int reg = 0; reg < 4; ++reg) {
                int t = 32 * wid + s * 16 + 4 * hi + reg;
                Ks[t * SQ + (nt - 4) * 16 + lo] = (_Float16)acc[nt][s][reg];
            }
    #pragma unroll
    for (int nt = 8; nt < 12; ++nt)
        #pragma unroll
        for (int s = 0; s < 2; ++s)
            #pragma unroll
            for (int reg = 0; reg < 4; ++reg) {
                int h = (nt - 8) * 16 + 4 * hi + reg;
                int t = 32 * wid + s * 16 + lo;
                Vt[h * SV + t] = (_Float16)acc[nt][s][reg];
            }
    __syncthreads();

    // ---- phase B: causal attention (verified structure, LDS operands) ----
    const int ctmax = 2 * wid + 1;

    f16x8 aq[2][2];
    #pragma unroll
    for (int rt = 0; rt < 2; ++rt)
        #pragma unroll
        for (int ks = 0; ks < 2; ++ks)
            aq[rt][ks] = *(const f16x8*)(Qs + (32 * wid + 16 * rt + lo) * SQ + 32 * ks + 8 * hi);

    f32x4 sacc[2][16] = {};
    #pragma unroll
    for (int ct = 0; ct < 16; ++ct) {
        if (ct <= ctmax) {
            #pragma unroll
            for (int ks = 0; ks < 2; ++ks) {
                f16x8 bk = *(const f16x8*)(Ks + (16 * ct + lo) * SQ + 32 * ks + 8 * hi);
                sacc[0][ct] = MFMA16(aq[0][ks], bk, sacc[0][ct]);
                sacc[1][ct] = MFMA16(aq[1][ks], bk, sacc[1][ct]);
            }
        }
    }

    #pragma unroll
    for (int rt = 0; rt < 2; ++rt) {
        #pragma unroll
        for (int reg = 0; reg < 4; ++reg) {
            const int rowg = 32 * wid + 16 * rt + 4 * hi + reg;
            float m = -1e30f;
            #pragma unroll
            for (int ct = 0; ct < 16; ++ct) if (ct <= ctmax) {
                float v = sacc[rt][ct][reg];
                v = (16 * ct + lo <= rowg) ? v : -1e30f;
                sacc[rt][ct][reg] = v;
                m = fmaxf(m, v);
            }
            #pragma unroll
            for (int s = 1; s < 16; s <<= 1) m = fmaxf(m, __shfl_xor(m, s, 16));
            float l = 0.f;
            #pragma unroll
            for (int ct = 0; ct < 16; ++ct) if (ct <= ctmax) {
                float v = sacc[rt][ct][reg];
                float p = (v > -1e29f) ? __expf(v - m) : 0.f;
                sacc[rt][ct][reg] = p;
                l += p;
            }
            #pragma unroll
            for (int s = 1; s < 16; s <<= 1) l += __shfl_xor(l, s, 16);
            float rinv = 1.f / l;
            #pragma unroll
            for (int ct = 0; ct < 16; ++ct) if (ct <= ctmax) sacc[rt][ct][reg] *= rinv;
        }
    }

    f32x4 oacc[2][4] = {};
    _Float16* Pw = Ps + wid * 32 * SP;
    const int kcmax = ctmax >> 2;
    #pragma unroll
    for (int kc = 0; kc < 4; ++kc) {
        if (kc <= kcmax) {
            #pragma unroll
            for (int rt = 0; rt < 2; ++rt)
                #pragma unroll
                for (int cc = 0; cc < 4; ++cc) {
                    const int ct = 4 * kc + cc;
                    #pragma unroll
                    for (int reg = 0; reg < 4; ++reg) {
                        float v = (ct <= ctmax) ? sacc[rt][ct][reg] : 0.f;
                        Pw[(16 * rt + 4 * hi + reg) * SP + cc * 16 + lo] = (_Float16)v;
                    }
                }
            asm volatile("s_waitcnt lgkmcnt(0)" ::: "memory");
            #pragma unroll
            for (int ks = 0; ks < 2; ++ks) {
                f16x8 p0 = *(const f16x8*)(Pw + lo * SP + 32 * ks + 8 * hi);
                f16x8 p1 = *(const f16x8*)(Pw + (16 + lo) * SP + 32 * ks + 8 * hi);
                #pragma unroll
                for (int ht = 0; ht < 4; ++ht) {
                    f16x8 bv = *(const f16x8*)(Vt + (16 * ht + lo) * SV + 64 * kc + 32 * ks + 8 * hi);
                    oacc[0][ht] = MFMA16(p0, bv, oacc[0][ht]);
                    oacc[1][ht] = MFMA16(p1, bv, oacc[1][ht]);
                }
            }
            asm volatile("s_waitcnt lgkmcnt(0)" ::: "memory");
        }
    }

    float* ob = out + (size_t)b * (T_ * H_);
    #pragma unroll
    for (int rt = 0; rt < 2; ++rt)
        #pragma unroll
        for (int ht = 0; ht < 4; ++ht)
            #pragma unroll
            for (int reg = 0; reg < 4; ++reg) {
                const int t = 32 * wid + 16 * rt + 4 * hi + reg;
                ob[t * H_ + 16 * ht + lo] = oacc[rt][ht][reg];
            }
}

extern "C" void kernel_launch(void* const* d_in, const int* in_sizes, int n_in,
                              void* d_out, int out_size, void* d_ws, size_t ws_size,
                              hipStream_t stream) {
    const float* x  = (const float*)d_in[0];
    const float* Wq = (const float*)d_in[1];
    const float* Wk = (const float*)d_in[2];
    const float* Wv = (const float*)d_in[3];
    float* out = (float*)d_out;
    (void)in_sizes; (void)n_in; (void)out_size; (void)ws_size;

    _Float16* Wf = (_Float16*)d_ws;                 // 147456 B

    w_fragpack<<<dim3(288), dim3(256), 0, stream>>>(Wq, Wk, Wv, Wf);
    hipFuncSetAttribute(reinterpret_cast<const void*>(head_fused),
                        hipFuncAttributeMaxDynamicSharedMemorySize, SMEM_BYTES);
    head_fused<<<dim3(B_), dim3(512), SMEM_BYTES, stream>>>(x, Wf, out);
}